// Round 11
// baseline (117.721 us; speedup 1.0000x reference)
//
#include <hip/hip_runtime.h>
#include <math.h>

#define IR_LEN  2000
#define PFRAME  80
#define NFRAMES 300
#define NBATCH  2
#define NROWS   (NBATCH*NFRAMES)     // 600
#define T_TOTAL (NFRAMES*PFRAME)     // 24000
#define NCOEF   25
#define TWO_PI  6.283185307179586f
#define GS      68                   // G row stride in floats
#define XWN     2160                 // logical x-window floats per block
#define XWPAD   2432                 // physical (4-float pad per 32)

#define XPHYS(B) ((B) + (((B) >> 5) << 2))

// ---------------------------------------------------------------------------
// Fully fused kernel: one block per (batch,frame) row. 600 blocks, 512 thr.
// (R10 structure, re-partitioned for 2x waves/CU: the R10 counters showed
//  occupancy 16% / VALUBusy 50% -> latency-bound, not throughput-bound.)
//   stage x : x window -> LDS (padded), first, to hide HBM latency.
//   phase E : E[f] -> LDS SoA + conjugate mirror; 4 f's/thread, base rotation
//             chained by const e^{-i pi/4}.
//   stage 1 : radix-2 over a (Te/To, w32 chain): thread = 4b x 1d -> d, d+32.
//   stage 2 : STEP2 (proven): thread = 1d x 4c (c = cg+8v via 8th roots).
//   FIR     : z[o] = <h, xwin(t0-80+o)>, o in [0,160); 24 chunks of 84 taps.
//   epilogue: y[t0-80+o] += tent(o) * z[o] via atomicAdd (y pre-zeroed).
// LDS: 34.8 KB union + 9.7 KB xw -> 3 blocks/CU cap (>= grid's 2.34).
// ---------------------------------------------------------------------------
__global__ __launch_bounds__(512) void minphase_fir_fused(
        const float* __restrict__ mc, const float* __restrict__ x,
        float* __restrict__ y) {
    __shared__ __align__(16) float U[8704];    // 34.8 KB union
    __shared__ __align__(16) float xws[XWPAD]; // 9.7 KB padded x window
    __shared__ float csh[NCOEF];
    float* const EHr = U;                      // [4096]      (phase E)
    float* const EHi = U + 4096;               // [4096]
    float* const Gr  = U;                      // [64*GS]     (stages 1/2)
    float* const Gi  = U + 4352;               // [64*GS]
    float* const hU  = U;                      // [2000]      (FIR phase)
    float* const red = U + 4224;               // [24 rows, stride 168]

    const int row   = blockIdx.x;
    const int batch = row / NFRAMES;
    const int frame = row - batch * NFRAMES;
    const int t0    = frame * PFRAME;
    const int t     = threadIdx.x;

    if (t < NCOEF) csh[t] = mc[row * NCOEF + t];

    // ---------------- stage x: pre-stage x window (padded) ----------------
    {
        const float* xb = x + batch * T_TOTAL;
        for (int j = t; j < XWN; j += 512) {
            const int xi = t0 - 2079 + j;
            const float v = (xi >= 0 && xi < T_TOTAL) ? xb[xi] : 0.0f;
            xws[XPHYS(j)] = v;
        }
    }
    __syncthreads();

    // ---------------- phase E (conjugate mirror, chained base) ------------
    {
        float bs, bc; sincosf(-(TWO_PI / 4096.0f) * (float)t, &bs, &bc);
        const float SC =  0.70710678118654752f;   // cos(pi/4)
        const float SS = -0.70710678118654752f;   // sin(-pi/4)
        #pragma unroll
        for (int ii = 0; ii < 4; ii++) {
            const int f = t + 512 * ii;                // 0..2047
            const float wc = bc, ws = bs;              // e^{-2pi i f/4096}
            { const float nr = bc * SC - bs * SS;      // advance base
              const float ni = bc * SS + bs * SC;
              bc = nr; bs = ni; }
            float cr = 1.0f, ci = 0.0f, Cr = 0.0f, Ci = 0.0f;
            #pragma unroll
            for (int k = 0; k < NCOEF; k++) {
                const float cc = csh[k];
                Cr += cc * cr; Ci += cc * ci;
                const float nr = cr * wc - ci * ws;
                const float ni = cr * ws + ci * wc;
                cr = nr; ci = ni;
            }
            const float m = expf(Cr);
            float si, co; sincosf(Ci, &si, &co);
            const float er = m * co, ei = m * si;
            EHr[f] = er; EHi[f] = ei;
            if (f > 0) { EHr[4096 - f] = er; EHi[4096 - f] = -ei; }
        }
        if (t == 0) {                                  // f = 2048
            float Cr = 0.0f, Ci = 0.0f;
            float cr = 1.0f, ci = 0.0f;
            #pragma unroll
            for (int k = 0; k < NCOEF; k++) {
                Cr += csh[k] * cr; Ci += csh[k] * ci;
                cr = -cr; ci = -ci;                    // e^{-i pi k} = (-1)^k
            }
            const float m = expf(Cr);
            float si, co; sincosf(Ci, &si, &co);
            EHr[2048] = m * co; EHi[2048] = m * si;
        }
    }
    __syncthreads();

    // ---------------- stage 1 (radix-2 over a: 4b x 1d, Te/To) ------------
    {
        const int b0 = (t & 15) * 4;
        const int d0 = t >> 4;                 // 0..31
        float Ter[4] = {0,0,0,0}, Tei[4] = {0,0,0,0};
        float Tor[4] = {0,0,0,0}, Toi[4] = {0,0,0,0};
        float wr_, wi_; sincosf((TWO_PI / 32.0f) * (float)d0, &wi_, &wr_);
        const float wr = wr_, wi = wi_;        // w32^{d0}
        float rr = 1.0f, ri = 0.0f;
        #pragma unroll 4
        for (int a2 = 0; a2 < 32; a2++) {
            const float4 vre = *(const float4*)&EHr[128 * a2 + b0];
            const float4 vie = *(const float4*)&EHi[128 * a2 + b0];
            const float4 vro = *(const float4*)&EHr[128 * a2 + 64 + b0];
            const float4 vio = *(const float4*)&EHi[128 * a2 + 64 + b0];
            const float ere[4] = {vre.x, vre.y, vre.z, vre.w};
            const float eie[4] = {vie.x, vie.y, vie.z, vie.w};
            const float ero[4] = {vro.x, vro.y, vro.z, vro.w};
            const float eio[4] = {vio.x, vio.y, vio.z, vio.w};
            #pragma unroll
            for (int i = 0; i < 4; i++) {
                Ter[i] += ere[i] * rr - eie[i] * ri;
                Tei[i] += ere[i] * ri + eie[i] * rr;
                Tor[i] += ero[i] * rr - eio[i] * ri;
                Toi[i] += ero[i] * ri + eio[i] * rr;
            }
            const float nr = rr * wr - ri * wi;
            const float ni = rr * wi + ri * wr;
            rr = nr; ri = ni;
        }
        __syncthreads();   // ALL E reads complete before G' overwrites U

        // radix-2 butterfly + bd/4096 twiddle + store
        float os_, oc_; sincosf((TWO_PI / 64.0f) * (float)d0, &os_, &oc_);
        #pragma unroll
        for (int i = 0; i < 4; i++) {
            const int b = b0 + i;
            const float ur = oc_ * Tor[i] - os_ * Toi[i];
            const float ui = oc_ * Toi[i] + os_ * Tor[i];
            const float pr = Ter[i] + ur, pi = Tei[i] + ui;
            const float mr = Ter[i] - ur, mi = Tei[i] - ui;
            float s, c;
            sincosf((TWO_PI / 4096.0f) * (float)(b * d0), &s, &c);
            Gr[b * GS + d0]      = pr * c - pi * s;
            Gi[b * GS + d0]      = pr * s + pi * c;
            sincosf((TWO_PI / 4096.0f) * (float)(b * (d0 + 32)), &s, &c);
            Gr[b * GS + d0 + 32] = mr * c - mi * s;
            Gi[b * GS + d0 + 32] = mr * s + mi * c;
        }
    }
    __syncthreads();

    // ---------------- stage 2 (STEP2, proven) -> h in registers ----------
    float hv[4];
    int   dl_, cg_;
    {
        const int dl = t & 63;                     // single d
        const int cg = t >> 6;                     // 0..7
        dl_ = dl; cg_ = cg;
        float swi_, swr_; sincosf((TWO_PI / 64.0f) * (float)cg, &swi_, &swr_);
        const float swr = swr_, swi = swi_;        // step e^{2pi i cg/64}
        float rr = 1.0f, ri = 0.0f;
        float acc0 = 0, acc1 = 0, acc2 = 0, acc3 = 0;
        int bb = 0;

#define S2C 0.70710678118654752f
#define STEP2(f8r, f8i, f16r, f16i, f24r, f24i)                                \
        {                                                                      \
            const float g_r = Gr[bb * GS + dl];                                \
            const float g_i = Gi[bb * GS + dl];                                \
            acc0 += g_r * rr - g_i * ri;                                       \
            { const float tr = rr*(f8r) - ri*(f8i), ti = rr*(f8i) + ri*(f8r);  \
              acc1 += g_r * tr - g_i * ti; }                                   \
            { const float tr = rr*(f16r) - ri*(f16i), ti = rr*(f16i) + ri*(f16r); \
              acc2 += g_r * tr - g_i * ti; }                                   \
            { const float tr = rr*(f24r) - ri*(f24i), ti = rr*(f24i) + ri*(f24r); \
              acc3 += g_r * tr - g_i * ti; }                                   \
            { const float nr = rr * swr - ri * swi;                            \
              const float ni = rr * swi + ri * swr;                            \
              rr = nr; ri = ni; }                                              \
            bb++;                                                              \
        }

        for (int grp = 0; grp < 8; grp++) {
            STEP2( 1.0f, 0.0f,   1.0f, 0.0f,   1.0f, 0.0f)
            STEP2( S2C,  S2C,    0.0f, 1.0f,  -S2C,  S2C)
            STEP2( 0.0f, 1.0f,  -1.0f, 0.0f,   0.0f,-1.0f)
            STEP2(-S2C,  S2C,    0.0f,-1.0f,   S2C,  S2C)
            STEP2(-1.0f, 0.0f,   1.0f, 0.0f,  -1.0f, 0.0f)
            STEP2(-S2C, -S2C,    0.0f, 1.0f,   S2C, -S2C)
            STEP2( 0.0f,-1.0f,  -1.0f, 0.0f,   0.0f, 1.0f)
            STEP2( S2C, -S2C,    0.0f,-1.0f,  -S2C, -S2C)
        }
#undef STEP2
        const float sc = 1.0f / 4096.0f;
        hv[0] = acc0 * sc; hv[1] = acc1 * sc;
        hv[2] = acc2 * sc; hv[3] = acc3 * sc;
    }
    __syncthreads();   // all G reads done; U is free

    // ---------------- h -> LDS ----------------
    #pragma unroll
    for (int v = 0; v < 4; v++) {
        const int c = cg_ + 8 * v;
        const int n = 64 * c + dl_;
        if (n < IR_LEN) hU[n] = hv[v];
    }
    __syncthreads();

    // ---------------- FIR: z[o], o in [0,160) ----------------
    if (t < 480) {
        const int o0 = (t % 20) * 8;
        const int kc = t / 20;                 // 0..23
        const int kb = kc * 84;
        const int ns = (kc == 23) ? 17 : 21;   // 23*84=1932, +68 = 2000
        float s0[8] = {0,0,0,0,0,0,0,0};
        int Bo = o0 + 1996 - kb;               // mult of 4, >= 0
        float4 w1 = *(const float4*)&xws[XPHYS(Bo + 4)];
        float4 w2 = *(const float4*)&xws[XPHYS(Bo + 8)];
        for (int s = 0; s < ns; s++) {
            const float4 w0 = *(const float4*)&xws[XPHYS(Bo)];
            const float4 ha = *(const float4*)&hU[kb + 4 * s];
            const float wv[12] = {w0.x, w0.y, w0.z, w0.w,
                                  w1.x, w1.y, w1.z, w1.w,
                                  w2.x, w2.y, w2.z, w2.w};
            const float hav[4] = {ha.x, ha.y, ha.z, ha.w};
            #pragma unroll
            for (int jo = 0; jo < 8; jo++) {
                #pragma unroll
                for (int jk = 0; jk < 4; jk++) {
                    s0[jo] += hav[jk] * wv[3 + jo - jk];
                }
            }
            w2 = w1; w1 = w0; Bo -= 4;
        }
        const int rb = kc * 168 + o0;
        *(float4*)&red[rb]     = make_float4(s0[0], s0[1], s0[2], s0[3]);
        *(float4*)&red[rb + 4] = make_float4(s0[4], s0[5], s0[6], s0[7]);
    }
    __syncthreads();

    // ---------------- epilogue: tent-weighted atomic scatter ----------------
    if (t < 160) {
        float z = 0.0f;
        #pragma unroll
        for (int kc = 0; kc < 24; kc++) z += red[kc * 168 + t];
        const int o = t;
        const int tout = t0 - PFRAME + o;
        float wgt = (o < PFRAME) ? (float)o * (1.0f / PFRAME)
                                 : (float)(160 - o) * (1.0f / PFRAME);
        if (frame == NFRAMES - 1 && o >= PFRAME) wgt = 1.0f;  // clamped h_next
        if (tout >= 0) {                       // frame 0 has no previous frame
            atomicAdd(&y[batch * T_TOTAL + tout], wgt * z);
        }
    }
}

extern "C" void kernel_launch(void* const* d_in, const int* in_sizes, int n_in,
                              void* d_out, int out_size, void* d_ws, size_t ws_size,
                              hipStream_t stream) {
    const float* x  = (const float*)d_in[0];   // (2, 24000)
    const float* mc = (const float*)d_in[1];   // (2, 300, 25)
    float* y = (float*)d_out;                  // (2, 24000)

    hipMemsetAsync(y, 0, (size_t)out_size * sizeof(float), stream);
    minphase_fir_fused<<<NROWS, 512, 0, stream>>>(mc, x, y);
}

// Round 12
// 95.432 us; speedup vs baseline: 1.2336x; 1.2336x over previous
//
#include <hip/hip_runtime.h>
#include <math.h>

#define IR_LEN  2000
#define PFRAME  80
#define NFRAMES 300
#define NBATCH  2
#define NROWS   (NBATCH*NFRAMES)     // 600
#define T_TOTAL (NFRAMES*PFRAME)     // 24000
#define NCOEF   25
#define TWO_PI  6.283185307179586f
#define GS      68                   // G row stride in floats
#define XWN     2160                 // logical x-window floats per block
#define XWPAD   2432                 // physical (4-float pad per 32)

#define XPHYS(B) ((B) + (((B) >> 5) << 2))

// fast hw trig: v_sin_f32/v_cos_f32 via __sinf/__cosf (absmax budget 9.9e-2,
// we run at ~4e-3 — plenty of headroom for ~2-ulp hw transcendentals).
__device__ __forceinline__ void fsincos(float a, float* s, float* c) {
    *s = __sinf(a); *c = __cosf(a);
}

// ---------------------------------------------------------------------------
// Fully fused kernel: one block per (batch,frame) row. 600 blocks, 256 thr.
// R10 structure (proven 53 us) + fast hw transcendentals + stage-1 prefetch.
//   stage x : x window -> LDS (padded), first, to hide HBM latency.
//   phase E : E[f] -> LDS SoA + conjugate mirror; 8 f's/thread, base rotation
//             chained by const e^{-i pi/8}; __expf/__sinf/__cosf.
//   stage 1 : radix-2 over a (Te/To, w32 chain): thread = 4b x 2d ->
//             (d,d+32),(d+1,d+33); 4 pts/b128 reuse (R11 lesson: keep it).
//   stage 2 : STEP2 (proven): thread = 2d x 4c.
//   FIR     : z[o] = <h, xwin(t0-80+o)>, o in [0,160); 12 chunks of 168.
//   epilogue: y[t0-80+o] += tent(o) * z[o] via atomicAdd (y pre-zeroed).
// LDS: 34.8 KB union + 9.7 KB xw -> 3 blocks/CU cap (>= grid's 2.34).
// ---------------------------------------------------------------------------
__global__ __launch_bounds__(256) void minphase_fir_fused(
        const float* __restrict__ mc, const float* __restrict__ x,
        float* __restrict__ y) {
    __shared__ __align__(16) float U[8704];    // 34.8 KB union
    __shared__ __align__(16) float xws[XWPAD]; // 9.7 KB padded x window
    __shared__ float csh[NCOEF];
    float* const EHr = U;                      // [4096]      (phase E)
    float* const EHi = U + 4096;               // [4096]
    float* const Gr  = U;                      // [64*GS]     (stages 1/2)
    float* const Gi  = U + 4352;               // [64*GS]
    float* const hU  = U;                      // [2000]      (FIR phase)
    float* const red = U + 4224;               // [12 rows, stride 168]

    const int row   = blockIdx.x;
    const int batch = row / NFRAMES;
    const int frame = row - batch * NFRAMES;
    const int t0    = frame * PFRAME;
    const int t     = threadIdx.x;

    if (t < NCOEF) csh[t] = mc[row * NCOEF + t];

    // ---------------- stage x: pre-stage x window (padded) ----------------
    {
        const float* xb = x + batch * T_TOTAL;
        for (int j = t; j < XWN; j += 256) {
            const int xi = t0 - 2079 + j;
            const float v = (xi >= 0 && xi < T_TOTAL) ? xb[xi] : 0.0f;
            xws[XPHYS(j)] = v;
        }
    }
    __syncthreads();

    // ---------------- phase E (conjugate mirror, chained base) ------------
    {
        float bs, bc; fsincos(-(TWO_PI / 4096.0f) * (float)t, &bs, &bc);
        const float SC =  0.923879532511287f;   // cos(pi/8)
        const float SS = -0.382683432365090f;   // sin(-pi/8)
        #pragma unroll 4
        for (int ii = 0; ii < 8; ii++) {
            const int f = t + 256 * ii;                // 0..2047
            const float wc = bc, ws = bs;              // e^{-2pi i f/4096}
            { const float nr = bc * SC - bs * SS;      // advance base
              const float ni = bc * SS + bs * SC;
              bc = nr; bs = ni; }
            float cr = 1.0f, ci = 0.0f, Cr = 0.0f, Ci = 0.0f;
            #pragma unroll
            for (int k = 0; k < NCOEF; k++) {
                const float cc = csh[k];
                Cr += cc * cr; Ci += cc * ci;
                const float nr = cr * wc - ci * ws;
                const float ni = cr * ws + ci * wc;
                cr = nr; ci = ni;
            }
            const float m = __expf(Cr);
            float si, co; fsincos(Ci, &si, &co);
            const float er = m * co, ei = m * si;
            EHr[f] = er; EHi[f] = ei;
            if (f > 0) { EHr[4096 - f] = er; EHi[4096 - f] = -ei; }
        }
        if (t == 0) {                                  // f = 2048
            float Cr = 0.0f, Ci = 0.0f;
            float cr = 1.0f, ci = 0.0f;
            #pragma unroll
            for (int k = 0; k < NCOEF; k++) {
                Cr += csh[k] * cr; Ci += csh[k] * ci;
                cr = -cr; ci = -ci;                    // e^{-i pi k} = (-1)^k
            }
            const float m = __expf(Cr);
            float si, co; fsincos(Ci, &si, &co);
            EHr[2048] = m * co; EHi[2048] = m * si;
        }
    }
    __syncthreads();

    // ---------------- stage 1 (radix-2 over a: 4b x 2d, Te/To) ------------
    {
        const int b0 = (t & 15) * 4;
        const int d0 = (t >> 4) * 2;           // 0,2,...,30
        float Ter[2][4], Tei[2][4], Tor[2][4], Toi[2][4];
        #pragma unroll
        for (int j = 0; j < 2; j++)
            #pragma unroll
            for (int i = 0; i < 4; i++) {
                Ter[j][i] = 0.0f; Tei[j][i] = 0.0f;
                Tor[j][i] = 0.0f; Toi[j][i] = 0.0f;
            }
        float rr[2], ri[2], wr[2], wi[2];
        #pragma unroll
        for (int j = 0; j < 2; j++) {
            float s, c; fsincos((TWO_PI / 32.0f) * (float)(d0 + j), &s, &c);
            wr[j] = c; wi[j] = s; rr[j] = 1.0f; ri[j] = 0.0f;
        }
        // explicit prefetch double-buffer over a2
        float4 vre = *(const float4*)&EHr[b0];
        float4 vie = *(const float4*)&EHi[b0];
        float4 vro = *(const float4*)&EHr[64 + b0];
        float4 vio = *(const float4*)&EHi[64 + b0];
        #pragma unroll 4
        for (int a2 = 0; a2 < 32; a2++) {
            const float4 cre = vre, cie = vie, cro = vro, cio = vio;
            if (a2 < 31) {
                const int nb = 128 * (a2 + 1) + b0;
                vre = *(const float4*)&EHr[nb];
                vie = *(const float4*)&EHi[nb];
                vro = *(const float4*)&EHr[nb + 64];
                vio = *(const float4*)&EHi[nb + 64];
            }
            const float ere[4] = {cre.x, cre.y, cre.z, cre.w};
            const float eie[4] = {cie.x, cie.y, cie.z, cie.w};
            const float ero[4] = {cro.x, cro.y, cro.z, cro.w};
            const float eio[4] = {cio.x, cio.y, cio.z, cio.w};
            #pragma unroll
            for (int j = 0; j < 2; j++) {
                #pragma unroll
                for (int i = 0; i < 4; i++) {
                    Ter[j][i] += ere[i] * rr[j] - eie[i] * ri[j];
                    Tei[j][i] += ere[i] * ri[j] + eie[i] * rr[j];
                    Tor[j][i] += ero[i] * rr[j] - eio[i] * ri[j];
                    Toi[j][i] += ero[i] * ri[j] + eio[i] * rr[j];
                }
                const float nr = rr[j] * wr[j] - ri[j] * wi[j];
                const float ni = rr[j] * wi[j] + ri[j] * wr[j];
                rr[j] = nr; ri[j] = ni;
            }
        }
        __syncthreads();   // ALL E reads complete before G' overwrites U

        // radix-2 butterfly + bd/4096 twiddle + store
        float os[2], oc[2];
        #pragma unroll
        for (int j = 0; j < 2; j++)
            fsincos((TWO_PI / 64.0f) * (float)(d0 + j), &os[j], &oc[j]);
        #pragma unroll
        for (int i = 0; i < 4; i++) {
            const int b = b0 + i;
            float gpr[2], gpi[2], gmr[2], gmi[2];
            #pragma unroll
            for (int j = 0; j < 2; j++) {
                const int d = d0 + j;
                const float ur = oc[j] * Tor[j][i] - os[j] * Toi[j][i];
                const float ui = oc[j] * Toi[j][i] + os[j] * Tor[j][i];
                const float pr = Ter[j][i] + ur, pi = Tei[j][i] + ui;
                const float mr = Ter[j][i] - ur, mi = Tei[j][i] - ui;
                float s, c;
                fsincos((TWO_PI / 4096.0f) * (float)(b * d), &s, &c);
                gpr[j] = pr * c - pi * s; gpi[j] = pr * s + pi * c;
                fsincos((TWO_PI / 4096.0f) * (float)(b * (d + 32)), &s, &c);
                gmr[j] = mr * c - mi * s; gmi[j] = mr * s + mi * c;
            }
            *(float2*)&Gr[b * GS + d0]      = make_float2(gpr[0], gpr[1]);
            *(float2*)&Gi[b * GS + d0]      = make_float2(gpi[0], gpi[1]);
            *(float2*)&Gr[b * GS + d0 + 32] = make_float2(gmr[0], gmr[1]);
            *(float2*)&Gi[b * GS + d0 + 32] = make_float2(gmi[0], gmi[1]);
        }
    }
    __syncthreads();

    // ---------------- stage 2 (STEP2, proven) -> h in registers ----------
    float hv[4][2];
    int   dl_, cg_;
    {
        const int dl = (t & 31) * 2;
        const int cg = t >> 5;                     // 0..7
        dl_ = dl; cg_ = cg;
        float swi_, swr_; fsincos((TWO_PI / 64.0f) * (float)cg, &swi_, &swr_);
        const float swr = swr_, swi = swi_;        // step e^{2pi i cg/64}
        float rr = 1.0f, ri = 0.0f;
        float acc00 = 0, acc01 = 0, acc10 = 0, acc11 = 0;
        float acc20 = 0, acc21 = 0, acc30 = 0, acc31 = 0;
        int bb = 0;

#define S2C 0.70710678118654752f
#define STEP2(f8r, f8i, f16r, f16i, f24r, f24i)                                \
        {                                                                      \
            const float2 g_r = *(const float2*)&Gr[bb * GS + dl];              \
            const float2 g_i = *(const float2*)&Gi[bb * GS + dl];              \
            acc00 += g_r.x * rr - g_i.x * ri;                                  \
            acc01 += g_r.y * rr - g_i.y * ri;                                  \
            { const float tr = rr*(f8r) - ri*(f8i), ti = rr*(f8i) + ri*(f8r);  \
              acc10 += g_r.x * tr - g_i.x * ti;                                \
              acc11 += g_r.y * tr - g_i.y * ti; }                              \
            { const float tr = rr*(f16r) - ri*(f16i), ti = rr*(f16i) + ri*(f16r); \
              acc20 += g_r.x * tr - g_i.x * ti;                                \
              acc21 += g_r.y * tr - g_i.y * ti; }                              \
            { const float tr = rr*(f24r) - ri*(f24i), ti = rr*(f24i) + ri*(f24r); \
              acc30 += g_r.x * tr - g_i.x * ti;                                \
              acc31 += g_r.y * tr - g_i.y * ti; }                              \
            { const float nr = rr * swr - ri * swi;                            \
              const float ni = rr * swi + ri * swr;                            \
              rr = nr; ri = ni; }                                              \
            bb++;                                                              \
        }

        for (int grp = 0; grp < 8; grp++) {
            STEP2( 1.0f, 0.0f,   1.0f, 0.0f,   1.0f, 0.0f)
            STEP2( S2C,  S2C,    0.0f, 1.0f,  -S2C,  S2C)
            STEP2( 0.0f, 1.0f,  -1.0f, 0.0f,   0.0f,-1.0f)
            STEP2(-S2C,  S2C,    0.0f,-1.0f,   S2C,  S2C)
            STEP2(-1.0f, 0.0f,   1.0f, 0.0f,  -1.0f, 0.0f)
            STEP2(-S2C, -S2C,    0.0f, 1.0f,   S2C, -S2C)
            STEP2( 0.0f,-1.0f,  -1.0f, 0.0f,   0.0f, 1.0f)
            STEP2( S2C, -S2C,    0.0f,-1.0f,  -S2C, -S2C)
        }
#undef STEP2
        const float sc = 1.0f / 4096.0f;
        hv[0][0] = acc00 * sc; hv[0][1] = acc01 * sc;
        hv[1][0] = acc10 * sc; hv[1][1] = acc11 * sc;
        hv[2][0] = acc20 * sc; hv[2][1] = acc21 * sc;
        hv[3][0] = acc30 * sc; hv[3][1] = acc31 * sc;
    }
    __syncthreads();   // all G reads done; U is free

    // ---------------- h -> LDS ----------------
    #pragma unroll
    for (int v = 0; v < 4; v++) {
        const int c = cg_ + 8 * v;
        const int n = 64 * c + dl_;
        if (n < IR_LEN)     hU[n]     = hv[v][0];
        if (n + 1 < IR_LEN) hU[n + 1] = hv[v][1];
    }
    __syncthreads();

    // ---------------- FIR: z[o], o in [0,160) ----------------
    if (t < 240) {
        const int o0 = (t % 20) * 8;
        const int kc = t / 20;                 // 0..11
        const int kb = kc * 168;
        const int ns = (kc == 11) ? 38 : 42;   // 11*168=1848, +152 = 2000
        float s0[8] = {0,0,0,0,0,0,0,0};
        int Bo = o0 + 1996 - kb;               // mult of 4, >= 0
        float4 w1 = *(const float4*)&xws[XPHYS(Bo + 4)];
        float4 w2 = *(const float4*)&xws[XPHYS(Bo + 8)];
        for (int s = 0; s < ns; s++) {
            const float4 w0 = *(const float4*)&xws[XPHYS(Bo)];
            const float4 ha = *(const float4*)&hU[kb + 4 * s];
            const float wv[12] = {w0.x, w0.y, w0.z, w0.w,
                                  w1.x, w1.y, w1.z, w1.w,
                                  w2.x, w2.y, w2.z, w2.w};
            const float hav[4] = {ha.x, ha.y, ha.z, ha.w};
            #pragma unroll
            for (int jo = 0; jo < 8; jo++) {
                #pragma unroll
                for (int jk = 0; jk < 4; jk++) {
                    s0[jo] += hav[jk] * wv[3 + jo - jk];
                }
            }
            w2 = w1; w1 = w0; Bo -= 4;
        }
        const int rb = kc * 168 + o0;
        *(float4*)&red[rb]     = make_float4(s0[0], s0[1], s0[2], s0[3]);
        *(float4*)&red[rb + 4] = make_float4(s0[4], s0[5], s0[6], s0[7]);
    }
    __syncthreads();

    // ---------------- epilogue: tent-weighted atomic scatter ----------------
    if (t < 160) {
        float z = 0.0f;
        #pragma unroll
        for (int kc = 0; kc < 12; kc++) z += red[kc * 168 + t];
        const int o = t;
        const int tout = t0 - PFRAME + o;
        float wgt = (o < PFRAME) ? (float)o * (1.0f / PFRAME)
                                 : (float)(160 - o) * (1.0f / PFRAME);
        if (frame == NFRAMES - 1 && o >= PFRAME) wgt = 1.0f;  // clamped h_next
        if (tout >= 0) {                       // frame 0 has no previous frame
            atomicAdd(&y[batch * T_TOTAL + tout], wgt * z);
        }
    }
}

extern "C" void kernel_launch(void* const* d_in, const int* in_sizes, int n_in,
                              void* d_out, int out_size, void* d_ws, size_t ws_size,
                              hipStream_t stream) {
    const float* x  = (const float*)d_in[0];   // (2, 24000)
    const float* mc = (const float*)d_in[1];   // (2, 300, 25)
    float* y = (float*)d_out;                  // (2, 24000)

    hipMemsetAsync(y, 0, (size_t)out_size * sizeof(float), stream);
    minphase_fir_fused<<<NROWS, 256, 0, stream>>>(mc, x, y);
}